// Round 5
// baseline (846.932 us; speedup 1.0000x reference)
//
#include <hip/hip_runtime.h>
#include <hip/hip_bf16.h>
#include <stdint.h>

// Problem constants (fixed by the reference)
#define VOCAB  100000
#define EDIM   128
#define HDIM   128
#define T_LEN  1024
#define BATCH  128
#define GDIM   512          // 4*HDIM
#define NROWS  (BATCH*T_LEN) // 131072
#define BN_EPS 1e-3f

using short8 = __attribute__((ext_vector_type(8))) short;  // 8 bf16 (4 VGPR)
using f32x4  = __attribute__((ext_vector_type(4))) float;  // MFMA accumulator

// ---- ws layout (bytes) ----
#define WS_SCALE  0u                          // 128 f32
#define WS_SHIFT  512u                        // 128 f32
#define WS_PSUM   1024u                       // 1024*128 f32 (reused as mask words after k_bn1_final)
#define WS_PSQ    (WS_PSUM + 524288u)         // 1024*128 f32
#define WS_HCAT   (WS_PSQ + 524288u)          // 128*256 f32
#define WS_FRAGS  (WS_HCAT + 131072u)         // 2*8*32*64*8 bf16 = 524288 B
#define WS_XN     (WS_FRAGS + 524288u)        // 131072*128 bf16 = 33554432 B
// total ~35.3 MB

// activation pre-scale constants folded into weights/biases:
//   sigmoid gates (i,f,o): g' = -log2(e)*g  -> sigm = rcp(1+exp2(g'))
//   tanh gate (c):         g' = 2*log2(e)*g -> tanh = 1-2*rcp(1+exp2(g'))
#define SGI_K (-1.4426950408889634f)
#define SGC_K ( 2.8853900817779268f)

__device__ __forceinline__ short f2bf(float f) {  // fp32 -> bf16 RNE
    uint32_t u = __float_as_uint(f);
    return (short)((u + 0x7fffu + ((u >> 16) & 1u)) >> 16);
}

// LDS-only barrier: do NOT drain vmcnt (in-flight global prefetches are
// register loads, compiler tracks their deps).
#define BAR() asm volatile("s_waitcnt lgkmcnt(0)\n\ts_barrier" ::: "memory")

// ---------------- K1a: BN1 partial sums (per-feature over B*T) ----------------
__global__ void k_bn1_partial(const int* __restrict__ ids,
                              const float* __restrict__ tab,
                              float* __restrict__ psum, float* __restrict__ psq) {
    __shared__ float ls[256], lq[256];
    int f = threadIdx.x & 127, rr = threadIdx.x >> 7;
    int r0 = blockIdx.x * 128;
    float s = 0.f, q = 0.f;
    for (int r = rr; r < 128; r += 2) {
        int id = ids[r0 + r];
        float v = tab[(size_t)id * EDIM + f];
        s += v; q += v * v;
    }
    ls[threadIdx.x] = s; lq[threadIdx.x] = q;
    __syncthreads();
    if (threadIdx.x < 128) {
        psum[blockIdx.x * 128 + f] = ls[f] + ls[f + 128];
        psq [blockIdx.x * 128 + f] = lq[f] + lq[f + 128];
    }
}

// ---------------- K1b: finalize BN1 -> scale/shift ----------------
__global__ void k_bn1_final(const float* __restrict__ psum, const float* __restrict__ psq,
                            const float* __restrict__ gamma, const float* __restrict__ beta,
                            float* __restrict__ scale, float* __restrict__ shift) {
    int f = threadIdx.x;  // 128 threads
    float s = 0.f, q = 0.f;
    for (int p = 0; p < 1024; ++p) { s += psum[p * 128 + f]; q += psq[p * 128 + f]; }
    const float inv_n = 1.0f / (float)NROWS;
    float m  = s * inv_n;
    float v  = q * inv_n - m * m;
    float sc = gamma[f] * rsqrtf(v + BN_EPS);
    scale[f] = sc;
    shift[f] = beta[f] - m * sc;
}

// ---------------- K1m: ballot-pack the sequence mask (1 bit per token) ----------------
__global__ void k_packmask(const int* __restrict__ ids, unsigned long long* __restrict__ mwords) {
    int gid = blockIdx.x * 1024 + threadIdx.x;   // 128 blocks x 1024 = 131072 tokens
    unsigned long long bal = __ballot(ids[gid] != 0);
    if ((threadIdx.x & 63) == 0) mwords[gid >> 6] = bal;
}

// ---------------- K2: embed gather + BN1 apply -> bf16 xn ----------------
__global__ void k_embed_norm(const int* __restrict__ ids,
                             const float* __restrict__ tab,
                             const float* __restrict__ scale,
                             const float* __restrict__ shift,
                             short* __restrict__ xn) {
    int gid = blockIdx.x * blockDim.x + threadIdx.x;  // 131072*16
    int row = gid >> 4, seg = gid & 15;
    int id  = ids[row];
    const float* src = tab + (size_t)id * EDIM + seg * 8;
    short8 out;
#pragma unroll
    for (int j = 0; j < 8; ++j) {
        float v = scale[seg * 8 + j] * src[j] + shift[seg * 8 + j];
        out[j] = f2bf(v);
    }
    *(short8*)(xn + (size_t)row * EDIM + seg * 8) = out;
}

// ---------------- K1c: prepack [W;U] into per-lane MFMA B-fragments ----------------
// frag id f = s*16 + gate*4 + kc   (s: 0=W, 1=U)
// B[k = 32*kc + 8*(l>>4) + j][col = 128*gate + 16*w8 + (l&15)]   (w8: 16-col tile 0..7)
// Weights pre-scaled per-gate for exp2-domain activations.
__global__ void k_prepack(const float* __restrict__ Wf, const float* __restrict__ Uf,
                          const float* __restrict__ Wb, const float* __restrict__ Ub,
                          short* __restrict__ frags) {
    int gid = blockIdx.x * blockDim.x + threadIdx.x;  // 32768
    int l  = gid & 63;
    int f  = (gid >> 6) & 31;
    int w  = (gid >> 11) & 7;
    int d  = gid >> 14;
    int s    = f >> 4;
    int gate = (f >> 2) & 3;
    int kc   = f & 3;
    const float* M = s ? (d ? Ub : Uf) : (d ? Wb : Wf);
    const float gs = (gate == 2) ? SGC_K : SGI_K;
    int rbase = 32 * kc + 8 * (l >> 4);
    int col   = 128 * gate + 16 * w + (l & 15);
    short8 out;
#pragma unroll
    for (int j = 0; j < 8; ++j) out[j] = f2bf(gs * M[(size_t)(rbase + j) * GDIM + col]);
    *(short8*)(frags + (size_t)gid * 8) = out;
}

#define MFMA(A, B, C) __builtin_amdgcn_mfma_f32_16x16x32_bf16((A), (B), (C), 0, 0, 0)
#define S8(x) __builtin_bit_cast(short8, x)

// ---------------- K4: the recurrence. One WG = one (direction, batch row). ----------------
// 4-WAVE build (issue-port model from R4 counters: step = MFMA_issue + VALU_issue, additive).
//  - 256 threads = 4 waves, 1 wave/SIMD. Each wave owns 32 h-cols = old tiles {2w, 2w+1}.
//  - 32 resident U frags/wave (two old waves' worth); W frags are per-step transient L2 loads
//    (issued at step top, consumed after the U*h block ~550cy later).
//  - per step/wave: 32 U*h MFMAs (8 chains, 4-deep, C=Z) + (J>=8) 4 XW MFMAs.
//    Per-SIMD MFMA issue unchanged vs 8-wave; per-SIMD VALU ~halves (the round-4 lever).
//  - xg layout [2][16][512] f32 gate-innermost; reads 2x ds_read_b128/thread/step.
//  - activation computed for 2 columns/thread (colA=32w+li, colB=+16); h write by l<16.
__global__ void __launch_bounds__(256, 1)
k_lstm(const short* __restrict__ xn,
       const short* __restrict__ frags,
       const unsigned long long* __restrict__ mwords,
       const float* __restrict__ bf_, const float* __restrict__ bb_,
       float* __restrict__ hcat) {
    const int d   = blockIdx.x >> 7;
    const int b   = blockIdx.x & 127;
    const int tid = threadIdx.x;
    const int w   = tid >> 6, l = tid & 63, g = l >> 4, li = l & 15;

    __shared__ float xg_lds[2][16][512];           // 64 KB: [buf][row][col*4+gate]
    __shared__ __align__(16) short h_s[2][HDIM];   // bf16 h, ping-pong

    float* const xgf = &xg_lds[0][0][0];

    // frag bases: this wave uses old tile slots 2w (A) and 2w+1 (B)
    const short8* wsA = (const short8*)frags + (size_t)(d * 8 + 2 * w) * 2048 + l;
    const short8* wsB = wsA + 2048;

    // U frags: NAMED, resident (32 frags = 128 VGPR)
    short8 uA00 = wsA[(16+0)*64],  uA01 = wsA[(16+1)*64],  uA02 = wsA[(16+2)*64],  uA03 = wsA[(16+3)*64];
    short8 uA10 = wsA[(16+4)*64],  uA11 = wsA[(16+5)*64],  uA12 = wsA[(16+6)*64],  uA13 = wsA[(16+7)*64];
    short8 uA20 = wsA[(16+8)*64],  uA21 = wsA[(16+9)*64],  uA22 = wsA[(16+10)*64], uA23 = wsA[(16+11)*64];
    short8 uA30 = wsA[(16+12)*64], uA31 = wsA[(16+13)*64], uA32 = wsA[(16+14)*64], uA33 = wsA[(16+15)*64];
    short8 uB00 = wsB[(16+0)*64],  uB01 = wsB[(16+1)*64],  uB02 = wsB[(16+2)*64],  uB03 = wsB[(16+3)*64];
    short8 uB10 = wsB[(16+4)*64],  uB11 = wsB[(16+5)*64],  uB12 = wsB[(16+6)*64],  uB13 = wsB[(16+7)*64];
    short8 uB20 = wsB[(16+8)*64],  uB21 = wsB[(16+9)*64],  uB22 = wsB[(16+10)*64], uB23 = wsB[(16+11)*64];
    short8 uB30 = wsB[(16+12)*64], uB31 = wsB[(16+13)*64], uB32 = wsB[(16+14)*64], uB33 = wsB[(16+15)*64];

    const float* bias = d ? bb_ : bf_;
    const float biaA0 = bias[0*128 + 32*w + li]      * SGI_K;
    const float biaA1 = bias[1*128 + 32*w + li]      * SGI_K;
    const float biaA2 = bias[2*128 + 32*w + li]      * SGC_K;
    const float biaA3 = bias[3*128 + 32*w + li]      * SGI_K;
    const float biaB0 = bias[0*128 + 32*w + 16 + li] * SGI_K;
    const float biaB1 = bias[1*128 + 32*w + 16 + li] * SGI_K;
    const float biaB2 = bias[2*128 + 32*w + 16 + li] * SGC_K;
    const float biaB3 = bias[3*128 + 32*w + 16 + li] * SGI_K;

    if (tid < HDIM) h_s[0][tid] = 0;
    float c_regA = 0.f, h_regA = 0.f, c_regB = 0.f, h_regB = 0.f;

    const f32x4 Z = {0.f, 0.f, 0.f, 0.f};

    // double-buffered xg read bases (per-thread col base; A=colA, B=colB)
    float* rdA_c = xgf + (32 * w + li) * 4;
    float* rdA_n = rdA_c + 8192;
    float* rdB_c = rdA_c + 64;
    float* rdB_n = rdB_c + 8192;

    // gather A-frags (named) for a chunk: lane l -> x[step 16c+li][k=32kc+8g+j]
    uint4 ga0, ga1, ga2, ga3;
#define GATHER(C_) { \
        int s0_ = 16 * (C_) + li; \
        int p_  = d ? (T_LEN - 1 - s0_) : s0_; \
        const uint4* gb_ = (const uint4*)xn + (size_t)(b * T_LEN + p_) * 16; \
        ga0 = gb_[g]; ga1 = gb_[4 + g]; ga2 = gb_[8 + g]; ga3 = gb_[12 + g]; \
    }

    // one xW col-tile: gate G_, side S_ (0: colA tile, 1: colB tile); W loaded transient
#define XWT(G_, S_, BIA_, DSTBASE_) { \
        const short8* wp_ = (S_) ? wsB : wsA; \
        short8 w0_ = wp_[((G_)*4+0)*64], w1_ = wp_[((G_)*4+1)*64]; \
        short8 w2_ = wp_[((G_)*4+2)*64], w3_ = wp_[((G_)*4+3)*64]; \
        f32x4 ax = {(BIA_), (BIA_), (BIA_), (BIA_)}; \
        ax = MFMA(S8(ga0), w0_, ax); \
        ax = MFMA(S8(ga1), w1_, ax); \
        ax = MFMA(S8(ga2), w2_, ax); \
        ax = MFMA(S8(ga3), w3_, ax); \
        float* wd_ = (DSTBASE_) + (S_) * 64 + (G_); \
        wd_[(4*g+0)*512] = ax[0]; wd_[(4*g+1)*512] = ax[1]; \
        wd_[(4*g+2)*512] = ax[2]; wd_[(4*g+3)*512] = ax[3]; \
    }

    // ---- prologue: chunk 0's xg into buffer 0 ----
    GATHER(0);
    XWT(0,0,biaA0, rdA_c - (32*w+li)*4)   // dst base = buf0 origin + per-thread col handled inside
    XWT(0,1,biaB0, rdA_c - (32*w+li)*4)
    XWT(1,0,biaA1, rdA_c - (32*w+li)*4)
    XWT(1,1,biaB1, rdA_c - (32*w+li)*4)
    XWT(2,0,biaA2, rdA_c - (32*w+li)*4)
    XWT(2,1,biaB2, rdA_c - (32*w+li)*4)
    XWT(3,0,biaA3, rdA_c - (32*w+li)*4)
    XWT(3,1,biaB3, rdA_c - (32*w+li)*4)
    __syncthreads();

    // oops: XWT's dst col must be the TILE's cols (c8*16+li), which for side S equals
    // (2w+S)*16+li == (32w+li) + S*16 -> base rdA_c already points at (32w+li)*4, and
    // XWT adds S*64 + G. So the correct base is the buffer origin + (32w+li)*4 = rdA_c
    // itself. The "- (32*w+li)*4 ... " above cancelled that; redo properly below is NOT
    // needed -- the 8 calls above wrote to buffer origin + S*64+G + rows, i.e. WRONG cols.
    // Correctness fix: recompute chunk 0 into buf0 with the right base now.
    GATHER(0);
    XWT(0,0,biaA0, rdA_c)
    XWT(0,1,biaB0, rdA_c)
    XWT(1,0,biaA1, rdA_c)
    XWT(1,1,biaB1, rdA_c)
    XWT(2,0,biaA2, rdA_c)
    XWT(2,1,biaB2, rdA_c)
    XWT(3,0,biaA3, rdA_c)
    XWT(3,1,biaB3, rdA_c)
    __syncthreads();

    f32x4 xva = *(const f32x4*)rdA_c;
    f32x4 xvb = *(const f32x4*)rdB_c;
    f32x4 yva, yvb;

#define XWBIA(J) ((J)==8?biaA0:(J)==9?biaB0:(J)==10?biaA1:(J)==11?biaB1: \
                  (J)==12?biaA2:(J)==13?biaB2:(J)==14?biaA3:biaB3)

    // One serial step. J compile-time. CV* = current xg f32x4, NV* = prefetch targets.
#define STEP(J, CVA, CVB, NVA, NVB) { \
        const uint4* hp_ = (const uint4*)(h_s[(J) & 1]); \
        uint4 hf0 = hp_[g], hf1 = hp_[4 + g], hf2 = hp_[8 + g], hf3 = hp_[12 + g]; \
        if (!((c == 63) && ((J) == 15))) { \
            const float* ra_ = ((J) < 15) ? rdA_c : rdA_n; \
            const float* rb_ = ((J) < 15) ? rdB_c : rdB_n; \
            NVA = *(const f32x4*)(ra_ + (((J) + 1) & 15) * 512); \
            NVB = *(const f32x4*)(rb_ + (((J) + 1) & 15) * 512); \
        } \
        f32x4 pA0, pA1, pA2, pA3, pB0, pB1, pB2, pB3; \
        pA0 = MFMA(S8(hf0), uA00, Z);  pB0 = MFMA(S8(hf0), uB00, Z); \
        pA1 = MFMA(S8(hf0), uA10, Z);  pB1 = MFMA(S8(hf0), uB10, Z); \
        pA2 = MFMA(S8(hf0), uA20, Z);  pB2 = MFMA(S8(hf0), uB20, Z); \
        pA3 = MFMA(S8(hf0), uA30, Z);  pB3 = MFMA(S8(hf0), uB30, Z); \
        pA0 = MFMA(S8(hf1), uA01, pA0); pB0 = MFMA(S8(hf1), uB01, pB0); \
        pA1 = MFMA(S8(hf1), uA11, pA1); pB1 = MFMA(S8(hf1), uB11, pB1); \
        pA2 = MFMA(S8(hf1), uA21, pA2); pB2 = MFMA(S8(hf1), uB21, pB2); \
        pA3 = MFMA(S8(hf1), uA31, pA3); pB3 = MFMA(S8(hf1), uB31, pB3); \
        pA0 = MFMA(S8(hf2), uA02, pA0); pB0 = MFMA(S8(hf2), uB02, pB0); \
        pA1 = MFMA(S8(hf2), uA12, pA1); pB1 = MFMA(S8(hf2), uB12, pB1); \
        pA2 = MFMA(S8(hf2), uA22, pA2); pB2 = MFMA(S8(hf2), uB22, pB2); \
        pA3 = MFMA(S8(hf2), uA32, pA3); pB3 = MFMA(S8(hf2), uB32, pB3); \
        pA0 = MFMA(S8(hf3), uA03, pA0); pB0 = MFMA(S8(hf3), uB03, pB0); \
        pA1 = MFMA(S8(hf3), uA13, pA1); pB1 = MFMA(S8(hf3), uB13, pB1); \
        pA2 = MFMA(S8(hf3), uA23, pA2); pB2 = MFMA(S8(hf3), uB23, pB2); \
        pA3 = MFMA(S8(hf3), uA33, pA3); pB3 = MFMA(S8(hf3), uB33, pB3); \
        if (((J) >= 8) && (c < 63)) { \
            XWT(((J)-8)>>1, (J)&1, XWBIA(J), rdA_n) \
        } \
        { \
            float giA = CVA[0] + pA0[0], gfA = CVA[1] + pA1[0]; \
            float gcA = CVA[2] + pA2[0], goA = CVA[3] + pA3[0]; \
            float giB = CVB[0] + pB0[0], gfB = CVB[1] + pB1[0]; \
            float gcB = CVB[2] + pB2[0], goB = CVB[3] + pB3[0]; \
            float siA = __builtin_amdgcn_rcpf(1.f + exp2f(giA)); \
            float sfA = __builtin_amdgcn_rcpf(1.f + exp2f(gfA)); \
            float soA = __builtin_amdgcn_rcpf(1.f + exp2f(goA)); \
            float tcA = __builtin_fmaf(-2.f, __builtin_amdgcn_rcpf(1.f + exp2f(gcA)), 1.f); \
            float siB = __builtin_amdgcn_rcpf(1.f + exp2f(giB)); \
            float sfB = __builtin_amdgcn_rcpf(1.f + exp2f(gfB)); \
            float soB = __builtin_amdgcn_rcpf(1.f + exp2f(goB)); \
            float tcB = __builtin_fmaf(-2.f, __builtin_amdgcn_rcpf(1.f + exp2f(gcB)), 1.f); \
            float cnA = __builtin_fmaf(sfA, c_regA, siA * tcA); \
            float cnB = __builtin_fmaf(sfB, c_regB, siB * tcB); \
            float thA = __builtin_fmaf(-2.f, __builtin_amdgcn_rcpf(1.f + exp2f(cnA * SGC_K)), 1.f); \
            float thB = __builtin_fmaf(-2.f, __builtin_amdgcn_rcpf(1.f + exp2f(cnB * SGC_K)), 1.f); \
            float hnA = soA * thA, hnB = soB * thB; \
            if (mb & (1u << (J))) { c_regA = cnA; h_regA = hnA; c_regB = cnB; h_regB = hnB; } \
            uint32_t pk_; \
            asm("v_cvt_pk_bf16_f32 %0, %1, %2" : "=v"(pk_) : "v"(h_regA), "v"(h_regB)); \
            if (l < 16) { \
                h_s[((J) + 1) & 1][32 * w + li]      = (short)pk_; \
                h_s[((J) + 1) & 1][32 * w + 16 + li] = (short)(pk_ >> 16); \
            } \
        } \
        BAR(); \
    }

#pragma unroll 1
    for (int c = 0; c < 64; ++c) {
        if (c < 63) GATHER(c + 1);   // consumed by XWT at J=8..15 (xW for chunk c+1)
        int cc_ = d ? 63 - c : c;
        unsigned long long mw_ = mwords[(size_t)b * 16 + (cc_ >> 2)];
        uint32_t mb = (uint32_t)(mw_ >> ((cc_ & 3) * 16)) & 0xFFFFu;
        if (d) mb = __builtin_bitreverse32(mb) >> 16;
        STEP(0,  xva, xvb, yva, yvb)
        STEP(1,  yva, yvb, xva, xvb)
        STEP(2,  xva, xvb, yva, yvb)
        STEP(3,  yva, yvb, xva, xvb)
        STEP(4,  xva, xvb, yva, yvb)
        STEP(5,  yva, yvb, xva, xvb)
        STEP(6,  xva, xvb, yva, yvb)
        STEP(7,  yva, yvb, xva, xvb)
        STEP(8,  xva, xvb, yva, yvb)
        STEP(9,  yva, yvb, xva, xvb)
        STEP(10, xva, xvb, yva, yvb)
        STEP(11, yva, yvb, xva, xvb)
        STEP(12, xva, xvb, yva, yvb)
        STEP(13, yva, yvb, xva, xvb)
        STEP(14, xva, xvb, yva, yvb)
        STEP(15, yva, yvb, xva, xvb)
        { float* t_;
          t_ = rdA_c; rdA_c = rdA_n; rdA_n = t_;
          t_ = rdB_c; rdB_c = rdB_n; rdB_n = t_; }
    }

    if (l < 16) {
        hcat[b * 256 + d * 128 + 32 * w + li]      = h_regA;  // fp32 final h
        hcat[b * 256 + d * 128 + 32 * w + 16 + li] = h_regB;
    }
}

// ---------------- K5: BN2 + dense(256->10) + softmax ----------------
__global__ void k_head(const float* __restrict__ hcat,
                       const float* __restrict__ gamma2, const float* __restrict__ beta2,
                       const float* __restrict__ Wd, const float* __restrict__ bd,
                       float* __restrict__ out) {
    __shared__ float sc_s[256], sh_s[256];
    __shared__ float logits[BATCH * 10];
    int tid = threadIdx.x;  // 1024
    if (tid < 256) {
        float s = 0.f, q = 0.f;
        for (int bb = 0; bb < BATCH; ++bb) { float v = hcat[bb * 256 + tid]; s += v; q += v * v; }
        float m  = s / (float)BATCH;
        float v  = q / (float)BATCH - m * m;
        float sc = gamma2[tid] * rsqrtf(v + BN_EPS);
        sc_s[tid] = sc;
        sh_s[tid] = beta2[tid] - m * sc;
    }
    __syncthreads();
    {
        int bb = tid >> 3, oq = tid & 7;   // thread -> (batch, out col); oq<2 also covers o=8,9
        float acc0 = bd[oq], acc1 = (oq < 2) ? bd[8 + oq] : 0.f;
        for (int k = 0; k < 256; ++k) {
            float hv = sc_s[k] * hcat[bb * 256 + k] + sh_s[k];
            acc0 += hv * Wd[k * 10 + oq];
            if (oq < 2) acc1 += hv * Wd[k * 10 + 8 + oq];
        }
        logits[bb * 10 + oq] = acc0;
        if (oq < 2) logits[bb * 10 + 8 + oq] = acc1;
    }
    __syncthreads();
    if (tid < BATCH) {
        float lm = -1e30f;
#pragma unroll
        for (int o = 0; o < 10; ++o) lm = fmaxf(lm, logits[tid * 10 + o]);
        float e[10], s = 0.f;
#pragma unroll
        for (int o = 0; o < 10; ++o) { e[o] = __expf(logits[tid * 10 + o] - lm); s += e[o]; }
        float inv = __builtin_amdgcn_rcpf(s);
#pragma unroll
        for (int o = 0; o < 10; ++o) out[tid * 10 + o] = e[o] * inv;
    }
}

extern "C" void kernel_launch(void* const* d_in, const int* in_sizes, int n_in,
                              void* d_out, int out_size, void* d_ws, size_t ws_size,
                              hipStream_t stream) {
    const int*   ids = (const int*)  d_in[0];
    const float* tab = (const float*)d_in[1];
    const float* g1  = (const float*)d_in[2];
    const float* b1  = (const float*)d_in[3];
    const float* Wf  = (const float*)d_in[4];
    const float* Uf  = (const float*)d_in[5];
    const float* bfv = (const float*)d_in[6];
    const float* Wb  = (const float*)d_in[7];
    const float* Ub  = (const float*)d_in[8];
    const float* bbv = (const float*)d_in[9];
    const float* g2  = (const float*)d_in[10];
    const float* b2  = (const float*)d_in[11];
    const float* Wd  = (const float*)d_in[12];
    const float* bd  = (const float*)d_in[13];

    char*  ws    = (char*)d_ws;
    float* scale = (float*)(ws + WS_SCALE);
    float* shift = (float*)(ws + WS_SHIFT);
    float* psum  = (float*)(ws + WS_PSUM);
    float* psq   = (float*)(ws + WS_PSQ);
    float* hcat  = (float*)(ws + WS_HCAT);
    short* fragp = (short*)(ws + WS_FRAGS);
    short* xnp   = (short*)(ws + WS_XN);
    unsigned long long* mwords = (unsigned long long*)(ws + WS_PSUM);  // reuse psum after k_bn1_final

    k_bn1_partial<<<1024, 256, 0, stream>>>(ids, tab, psum, psq);
    k_bn1_final  <<<1, 128, 0, stream>>>(psum, psq, g1, b1, scale, shift);
    k_packmask   <<<128, 1024, 0, stream>>>(ids, mwords);   // after bn1_final: overwrites psum region
    k_embed_norm <<<8192, 256, 0, stream>>>(ids, tab, scale, shift, xnp);
    k_prepack    <<<128, 256, 0, stream>>>(Wf, Uf, Wb, Ub, fragp);
    k_lstm       <<<256, 256, 0, stream>>>(xnp, fragp, mwords, bfv, bbv, hcat);
    k_head       <<<1, 1024, 0, stream>>>(hcat, g2, b2, Wd, bd, (float*)d_out);
}

// Round 6
// 650.454 us; speedup vs baseline: 1.3021x; 1.3021x over previous
//
#include <hip/hip_runtime.h>
#include <hip/hip_bf16.h>
#include <stdint.h>

// Problem constants (fixed by the reference)
#define VOCAB  100000
#define EDIM   128
#define HDIM   128
#define T_LEN  1024
#define BATCH  128
#define GDIM   512          // 4*HDIM
#define NROWS  (BATCH*T_LEN) // 131072
#define BN_EPS 1e-3f

using short8 = __attribute__((ext_vector_type(8))) short;  // 8 bf16 (4 VGPR)
using f32x4  = __attribute__((ext_vector_type(4))) float;  // MFMA accumulator

// ---- ws layout (bytes) ----
#define WS_SCALE  0u                          // 128 f32
#define WS_SHIFT  512u                        // 128 f32
#define WS_PSUM   1024u                       // 1024*128 f32 (reused as mask words after k_bn1_final)
#define WS_PSQ    (WS_PSUM + 524288u)         // 1024*128 f32
#define WS_HCAT   (WS_PSQ + 524288u)          // 128*256 f32
#define WS_FRAGS  (WS_HCAT + 131072u)         // 2*8*32*64*8 bf16 = 524288 B
#define WS_XN     (WS_FRAGS + 524288u)        // 131072*128 bf16 = 33554432 B
// total ~35.3 MB

// activation pre-scale constants folded into weights/biases:
//   sigmoid gates (i,f,o): g' = -log2(e)*g  -> sigm = rcp(1+exp2(g'))
//   tanh gate (c):         g' = 2*log2(e)*g -> tanh = 1-2*rcp(1+exp2(g'))
// cell state kept PRE-SCALED: cK = SGC_K * c, so tanh(c_new) needs no extra mul.
#define SGI_K  (-1.4426950408889634f)
#define SGC_K  ( 2.8853900817779268f)
#define NSGC2  (-5.7707801635558536f)   // -2*SGC_K

__device__ __forceinline__ short f2bf(float f) {  // fp32 -> bf16 RNE
    uint32_t u = __float_as_uint(f);
    return (short)((u + 0x7fffu + ((u >> 16) & 1u)) >> 16);
}

// LDS-only barrier: do NOT drain vmcnt (in-flight global prefetches are
// register loads, compiler tracks their deps).
#define BAR() asm volatile("s_waitcnt lgkmcnt(0)\n\ts_barrier" ::: "memory")

// ---------------- K1a: BN1 partial sums (per-feature over B*T) ----------------
__global__ void k_bn1_partial(const int* __restrict__ ids,
                              const float* __restrict__ tab,
                              float* __restrict__ psum, float* __restrict__ psq) {
    __shared__ float ls[256], lq[256];
    int f = threadIdx.x & 127, rr = threadIdx.x >> 7;
    int r0 = blockIdx.x * 128;
    float s = 0.f, q = 0.f;
    for (int r = rr; r < 128; r += 2) {
        int id = ids[r0 + r];
        float v = tab[(size_t)id * EDIM + f];
        s += v; q += v * v;
    }
    ls[threadIdx.x] = s; lq[threadIdx.x] = q;
    __syncthreads();
    if (threadIdx.x < 128) {
        psum[blockIdx.x * 128 + f] = ls[f] + ls[f + 128];
        psq [blockIdx.x * 128 + f] = lq[f] + lq[f + 128];
    }
}

// ---------------- K1b: finalize BN1 -> scale/shift ----------------
__global__ void k_bn1_final(const float* __restrict__ psum, const float* __restrict__ psq,
                            const float* __restrict__ gamma, const float* __restrict__ beta,
                            float* __restrict__ scale, float* __restrict__ shift) {
    int f = threadIdx.x;  // 128 threads
    float s = 0.f, q = 0.f;
    for (int p = 0; p < 1024; ++p) { s += psum[p * 128 + f]; q += psq[p * 128 + f]; }
    const float inv_n = 1.0f / (float)NROWS;
    float m  = s * inv_n;
    float v  = q * inv_n - m * m;
    float sc = gamma[f] * rsqrtf(v + BN_EPS);
    scale[f] = sc;
    shift[f] = beta[f] - m * sc;
}

// ---------------- K1m: ballot-pack the sequence mask (1 bit per token) ----------------
__global__ void k_packmask(const int* __restrict__ ids, unsigned long long* __restrict__ mwords) {
    int gid = blockIdx.x * 1024 + threadIdx.x;   // 128 blocks x 1024 = 131072 tokens
    unsigned long long bal = __ballot(ids[gid] != 0);
    if ((threadIdx.x & 63) == 0) mwords[gid >> 6] = bal;
}

// ---------------- K2: embed gather + BN1 apply -> bf16 xn ----------------
__global__ void k_embed_norm(const int* __restrict__ ids,
                             const float* __restrict__ tab,
                             const float* __restrict__ scale,
                             const float* __restrict__ shift,
                             short* __restrict__ xn) {
    int gid = blockIdx.x * blockDim.x + threadIdx.x;  // 131072*16
    int row = gid >> 4, seg = gid & 15;
    int id  = ids[row];
    const float* src = tab + (size_t)id * EDIM + seg * 8;
    short8 out;
#pragma unroll
    for (int j = 0; j < 8; ++j) {
        float v = scale[seg * 8 + j] * src[j] + shift[seg * 8 + j];
        out[j] = f2bf(v);
    }
    *(short8*)(xn + (size_t)row * EDIM + seg * 8) = out;
}

// ---------------- K1c: prepack [W;U] into per-lane MFMA B-fragments ----------------
// frag id f = s*16 + gate*4 + kc   (s: 0=W, 1=U)
// B[k = 32*kc + 8*(l>>4) + j][col = 128*gate + 16*w + (l&15)]
// Weights pre-scaled per-gate for exp2-domain activations.
__global__ void k_prepack(const float* __restrict__ Wf, const float* __restrict__ Uf,
                          const float* __restrict__ Wb, const float* __restrict__ Ub,
                          short* __restrict__ frags) {
    int gid = blockIdx.x * blockDim.x + threadIdx.x;  // 32768
    int l  = gid & 63;
    int f  = (gid >> 6) & 31;
    int w  = (gid >> 11) & 7;
    int d  = gid >> 14;
    int s    = f >> 4;
    int gate = (f >> 2) & 3;
    int kc   = f & 3;
    const float* M = s ? (d ? Ub : Uf) : (d ? Wb : Wf);
    const float gs = (gate == 2) ? SGC_K : SGI_K;
    int rbase = 32 * kc + 8 * (l >> 4);
    int col   = 128 * gate + 16 * w + (l & 15);
    short8 out;
#pragma unroll
    for (int j = 0; j < 8; ++j) out[j] = f2bf(gs * M[(size_t)(rbase + j) * GDIM + col]);
    *(short8*)(frags + (size_t)gid * 8) = out;
}

#define MFMA(A, B, C) __builtin_amdgcn_mfma_f32_16x16x32_bf16((A), (B), (C), 0, 0, 0)
#define S8(x) __builtin_bit_cast(short8, x)

// ---------------- K4: the recurrence. One WG = one (direction, batch row). ----------------
// 8 waves, 2/SIMD (R2/R4-proven machine config). Per-step critical chain shortened:
//  - gates f,i,c issued FIRST as 3 interleaved 4-deep MFMA chains with xg preloaded in
//    the C-operand elem0 (persistent accs; elems 1-3 carry benign garbage) -> activation's
//    cn path starts at MFMA 12/16, with 2 fewer dependent VALU ops
//  - gate o LAST as 2x 2-deep chains + 1 add; its sigmoid overlaps th's transcendentals
//  - cell state pre-scaled (cK = SGC_K*c): tanh(c_new) argument mul eliminated
//  - xg layout [2][16][512] gate-innermost: ONE ds_read_b128 per step (R2-proven)
//  - XWGATE at J=8..11 before the U*h block (R2-proven position)
__global__ void __launch_bounds__(512, 2)
k_lstm(const short* __restrict__ xn,
       const short* __restrict__ frags,
       const unsigned long long* __restrict__ mwords,
       const float* __restrict__ bf_, const float* __restrict__ bb_,
       float* __restrict__ hcat) {
    const int d   = blockIdx.x >> 7;
    const int b   = blockIdx.x & 127;
    const int tid = threadIdx.x;
    const int w   = tid >> 6, l = tid & 63, g = l >> 4, li = l & 15;

    __shared__ float xg_lds[2][16][512];           // 64 KB: [buf][row][col*4+gate]
    __shared__ __align__(16) short h_s[2][HDIM];   // bf16 h, ping-pong

    float* const xgf = &xg_lds[0][0][0];
    float* const xgr = xgf + (w * 16 + li) * 4;    // per-thread read base (col's float4)

    const short8* wsrc = (const short8*)frags + (size_t)(d * 8 + w) * 32 * 64 + l;

    // W frags: NAMED, resident
    short8 wq00 = wsrc[0*64],  wq01 = wsrc[1*64],  wq02 = wsrc[2*64],  wq03 = wsrc[3*64];
    short8 wq10 = wsrc[4*64],  wq11 = wsrc[5*64],  wq12 = wsrc[6*64],  wq13 = wsrc[7*64];
    short8 wq20 = wsrc[8*64],  wq21 = wsrc[9*64],  wq22 = wsrc[10*64], wq23 = wsrc[11*64];
    short8 wq30 = wsrc[12*64], wq31 = wsrc[13*64], wq32 = wsrc[14*64], wq33 = wsrc[15*64];

    // U frags: NAMED, resident
    short8 u00 = wsrc[(16+0)*64],  u01 = wsrc[(16+1)*64],  u02 = wsrc[(16+2)*64],  u03 = wsrc[(16+3)*64];
    short8 u10 = wsrc[(16+4)*64],  u11 = wsrc[(16+5)*64],  u12 = wsrc[(16+6)*64],  u13 = wsrc[(16+7)*64];
    short8 u20 = wsrc[(16+8)*64],  u21 = wsrc[(16+9)*64],  u22 = wsrc[(16+10)*64], u23 = wsrc[(16+11)*64];
    short8 u30 = wsrc[(16+12)*64], u31 = wsrc[(16+13)*64], u32 = wsrc[(16+14)*64], u33 = wsrc[(16+15)*64];

    const float* bias = d ? bb_ : bf_;
    const float bia0 = bias[0*128 + w*16 + li] * SGI_K;
    const float bia1 = bias[1*128 + w*16 + li] * SGI_K;
    const float bia2 = bias[2*128 + w*16 + li] * SGC_K;
    const float bia3 = bias[3*128 + w*16 + li] * SGI_K;

    if (tid < HDIM) h_s[0][tid] = 0;
    float cK_reg = 0.f, h_reg = 0.f;   // cell state pre-scaled by SGC_K

    // Persistent accumulators: elem0 is reloaded each step (xg preload); elems 1-3
    // accumulate stale garbage across steps (never read, element-wise independent).
    f32x4 a0 = {0.f,0.f,0.f,0.f}, a1 = {0.f,0.f,0.f,0.f}, a2 = {0.f,0.f,0.f,0.f};
    f32x4 a3a = {0.f,0.f,0.f,0.f}, a3b = {0.f,0.f,0.f,0.f};

    // gather A-frags (named) for a chunk: lane l -> x[step 16c+li][k=32kc+8g+j]
    uint4 ga0, ga1, ga2, ga3;
#define GATHER(C_) { \
        int s0_ = 16 * (C_) + li; \
        int p_  = d ? (T_LEN - 1 - s0_) : s0_; \
        const uint4* gb_ = (const uint4*)xn + (size_t)(b * T_LEN + p_) * 16; \
        ga0 = gb_[g]; ga1 = gb_[4 + g]; ga2 = gb_[8 + g]; ga3 = gb_[12 + g]; \
    }

    // xW for one gate: 4 MFMAs (A rows = 16 timesteps), store D rows to [row][col*4+gate]
#define XWGATE(GG, W0, W1, W2, W3, BIA, BUF) { \
        f32x4 ax = {(BIA), (BIA), (BIA), (BIA)}; \
        ax = MFMA(S8(ga0), W0, ax); \
        ax = MFMA(S8(ga1), W1, ax); \
        ax = MFMA(S8(ga2), W2, ax); \
        ax = MFMA(S8(ga3), W3, ax); \
        float* dst_ = xgf + (BUF) * 8192 + (w * 16 + li) * 4 + (GG); \
        dst_[(4*g+0)*512] = ax[0]; dst_[(4*g+1)*512] = ax[1]; \
        dst_[(4*g+2)*512] = ax[2]; dst_[(4*g+3)*512] = ax[3]; \
    }

    // ---- prologue: compute chunk 0's xg into buffer 0 ----
    GATHER(0);
    XWGATE(0, wq00, wq01, wq02, wq03, bia0, 0);
    XWGATE(1, wq10, wq11, wq12, wq13, bia1, 0);
    XWGATE(2, wq20, wq21, wq22, wq23, bia2, 0);
    XWGATE(3, wq30, wq31, wq32, wq33, bia3, 0);
    __syncthreads();

    float xa0, xa1, xa2, xa3, xb0, xb1, xb2, xb3;
    {
        const f32x4 xv0 = *(const f32x4*)(xgr);
        xa0 = xv0[0]; xa1 = xv0[1]; xa2 = xv0[2]; xa3 = xv0[3];
    }

    // One serial step. J compile-time. XC* = current xg scalars, XN* = prefetch targets.
#define STEP(J, XC0, XC1, XC2, XC3, XN0, XN1, XN2, XN3) { \
        const uint4* hp_ = (const uint4*)(h_s[(J) & 1]); \
        uint4 hf0 = hp_[g], hf1 = hp_[4 + g], hf2 = hp_[8 + g], hf3 = hp_[12 + g]; \
        if (c < 63) { \
            if ((J) == 8)  XWGATE(0, wq00, wq01, wq02, wq03, bia0, ((c + 1) & 1)); \
            if ((J) == 9)  XWGATE(1, wq10, wq11, wq12, wq13, bia1, ((c + 1) & 1)); \
            if ((J) == 10) XWGATE(2, wq20, wq21, wq22, wq23, bia2, ((c + 1) & 1)); \
            if ((J) == 11) XWGATE(3, wq30, wq31, wq32, wq33, bia3, ((c + 1) & 1)); \
        } \
        /* xg preloaded into acc elem0; gates f(a1), i(a0), c(a2) as 3 interleaved */ \
        /* 4-deep chains FIRST; gate o (a3a/a3b) last as 2x2-deep + add */ \
        a0[0] = (XC0); a1[0] = (XC1); a2[0] = (XC2); a3a[0] = (XC3); a3b[0] = 0.f; \
        a1 = MFMA(S8(hf0), u10, a1); \
        a0 = MFMA(S8(hf0), u00, a0); \
        a2 = MFMA(S8(hf0), u20, a2); \
        a1 = MFMA(S8(hf1), u11, a1); \
        a0 = MFMA(S8(hf1), u01, a0); \
        a2 = MFMA(S8(hf1), u21, a2); \
        a1 = MFMA(S8(hf2), u12, a1); \
        a0 = MFMA(S8(hf2), u02, a0); \
        a2 = MFMA(S8(hf2), u22, a2); \
        a1 = MFMA(S8(hf3), u13, a1); \
        a0 = MFMA(S8(hf3), u03, a0); \
        a2 = MFMA(S8(hf3), u23, a2); \
        a3a = MFMA(S8(hf0), u30, a3a); \
        a3b = MFMA(S8(hf2), u32, a3b); \
        a3a = MFMA(S8(hf1), u31, a3a); \
        a3b = MFMA(S8(hf3), u33, a3b); \
        if (!((c == 63) && ((J) == 15))) { \
            const f32x4 xv_ = *(const f32x4*)(xgr + (((J) < 15) ? (c & 1) : ((c + 1) & 1)) * 8192 \
                                                  + (((J) + 1) & 15) * 512); \
            XN0 = xv_[0]; XN1 = xv_[1]; XN2 = xv_[2]; XN3 = xv_[3]; \
        } \
        { \
            float gf = a1[0], gi = a0[0], gc = a2[0]; \
            float sf = __builtin_amdgcn_rcpf(1.f + exp2f(gf)); \
            float si = __builtin_amdgcn_rcpf(1.f + exp2f(gi)); \
            float tcK = __builtin_fmaf(NSGC2, __builtin_amdgcn_rcpf(1.f + exp2f(gc)), SGC_K); \
            float cnK = __builtin_fmaf(sf, cK_reg, si * tcK); \
            float th  = __builtin_fmaf(-2.f, __builtin_amdgcn_rcpf(1.f + exp2f(cnK)), 1.f); \
            float go  = a3a[0] + a3b[0]; \
            float so  = __builtin_amdgcn_rcpf(1.f + exp2f(go)); \
            float hn  = so * th; \
            if (mb & (1u << (J))) { cK_reg = cnK; h_reg = hn; } \
            uint32_t pk_; \
            asm("v_cvt_pk_bf16_f32 %0, %1, %2" : "=v"(pk_) : "v"(h_reg), "v"(h_reg)); \
            if (l < 16) h_s[((J) + 1) & 1][w * 16 + li] = (short)pk_; \
        } \
        BAR(); \
    }

#pragma unroll 1
    for (int c = 0; c < 64; ++c) {
        if (c < 63) GATHER(c + 1);   // consumed at J=8..11 (xW for chunk c+1)
        int cc_ = d ? 63 - c : c;
        unsigned long long mw_ = mwords[(size_t)b * 16 + (cc_ >> 2)];
        uint32_t mb = (uint32_t)(mw_ >> ((cc_ & 3) * 16)) & 0xFFFFu;
        if (d) mb = __builtin_bitreverse32(mb) >> 16;
        STEP(0,  xa0, xa1, xa2, xa3, xb0, xb1, xb2, xb3)
        STEP(1,  xb0, xb1, xb2, xb3, xa0, xa1, xa2, xa3)
        STEP(2,  xa0, xa1, xa2, xa3, xb0, xb1, xb2, xb3)
        STEP(3,  xb0, xb1, xb2, xb3, xa0, xa1, xa2, xa3)
        STEP(4,  xa0, xa1, xa2, xa3, xb0, xb1, xb2, xb3)
        STEP(5,  xb0, xb1, xb2, xb3, xa0, xa1, xa2, xa3)
        STEP(6,  xa0, xa1, xa2, xa3, xb0, xb1, xb2, xb3)
        STEP(7,  xb0, xb1, xb2, xb3, xa0, xa1, xa2, xa3)
        STEP(8,  xa0, xa1, xa2, xa3, xb0, xb1, xb2, xb3)
        STEP(9,  xb0, xb1, xb2, xb3, xa0, xa1, xa2, xa3)
        STEP(10, xa0, xa1, xa2, xa3, xb0, xb1, xb2, xb3)
        STEP(11, xb0, xb1, xb2, xb3, xa0, xa1, xa2, xa3)
        STEP(12, xa0, xa1, xa2, xa3, xb0, xb1, xb2, xb3)
        STEP(13, xb0, xb1, xb2, xb3, xa0, xa1, xa2, xa3)
        STEP(14, xa0, xa1, xa2, xa3, xb0, xb1, xb2, xb3)
        STEP(15, xb0, xb1, xb2, xb3, xa0, xa1, xa2, xa3)
    }

    if (l < 16) hcat[b * 256 + d * 128 + w * 16 + li] = h_reg;  // fp32 final h
}

// ---------------- K5: BN2 + dense(256->10) + softmax ----------------
__global__ void k_head(const float* __restrict__ hcat,
                       const float* __restrict__ gamma2, const float* __restrict__ beta2,
                       const float* __restrict__ Wd, const float* __restrict__ bd,
                       float* __restrict__ out) {
    __shared__ float sc_s[256], sh_s[256];
    __shared__ float logits[BATCH * 10];
    int tid = threadIdx.x;  // 1024
    if (tid < 256) {
        float s = 0.f, q = 0.f;
        for (int bb = 0; bb < BATCH; ++bb) { float v = hcat[bb * 256 + tid]; s += v; q += v * v; }
        float m  = s / (float)BATCH;
        float v  = q / (float)BATCH - m * m;
        float sc = gamma2[tid] * rsqrtf(v + BN_EPS);
        sc_s[tid] = sc;
        sh_s[tid] = beta2[tid] - m * sc;
    }
    __syncthreads();
    {
        int bb = tid >> 3, oq = tid & 7;   // thread -> (batch, out col); oq<2 also covers o=8,9
        float acc0 = bd[oq], acc1 = (oq < 2) ? bd[8 + oq] : 0.f;
        for (int k = 0; k < 256; ++k) {
            float hv = sc_s[k] * hcat[bb * 256 + k] + sh_s[k];
            acc0 += hv * Wd[k * 10 + oq];
            if (oq < 2) acc1 += hv * Wd[k * 10 + 8 + oq];
        }
        logits[bb * 10 + oq] = acc0;
        if (oq < 2) logits[bb * 10 + 8 + oq] = acc1;
    }
    __syncthreads();
    if (tid < BATCH) {
        float lm = -1e30f;
#pragma unroll
        for (int o = 0; o < 10; ++o) lm = fmaxf(lm, logits[tid * 10 + o]);
        float e[10], s = 0.f;
#pragma unroll
        for (int o = 0; o < 10; ++o) { e[o] = __expf(logits[tid * 10 + o] - lm); s += e[o]; }
        float inv = __builtin_amdgcn_rcpf(s);
#pragma unroll
        for (int o = 0; o < 10; ++o) out[tid * 10 + o] = e[o] * inv;
    }
}

extern "C" void kernel_launch(void* const* d_in, const int* in_sizes, int n_in,
                              void* d_out, int out_size, void* d_ws, size_t ws_size,
                              hipStream_t stream) {
    const int*   ids = (const int*)  d_in[0];
    const float* tab = (const float*)d_in[1];
    const float* g1  = (const float*)d_in[2];
    const float* b1  = (const float*)d_in[3];
    const float* Wf  = (const float*)d_in[4];
    const float* Uf  = (const float*)d_in[5];
    const float* bfv = (const float*)d_in[6];
    const float* Wb  = (const float*)d_in[7];
    const float* Ub  = (const float*)d_in[8];
    const float* bbv = (const float*)d_in[9];
    const float* g2  = (const float*)d_in[10];
    const float* b2  = (const float*)d_in[11];
    const float* Wd  = (const float*)d_in[12];
    const float* bd  = (const float*)d_in[13];

    char*  ws    = (char*)d_ws;
    float* scale = (float*)(ws + WS_SCALE);
    float* shift = (float*)(ws + WS_SHIFT);
    float* psum  = (float*)(ws + WS_PSUM);
    float* psq   = (float*)(ws + WS_PSQ);
    float* hcat  = (float*)(ws + WS_HCAT);
    short* fragp = (short*)(ws + WS_FRAGS);
    short* xnp   = (short*)(ws + WS_XN);
    unsigned long long* mwords = (unsigned long long*)(ws + WS_PSUM);  // reuse psum after k_bn1_final

    k_bn1_partial<<<1024, 256, 0, stream>>>(ids, tab, psum, psq);
    k_bn1_final  <<<1, 128, 0, stream>>>(psum, psq, g1, b1, scale, shift);
    k_packmask   <<<128, 1024, 0, stream>>>(ids, mwords);   // after bn1_final: overwrites psum region
    k_embed_norm <<<8192, 256, 0, stream>>>(ids, tab, scale, shift, xnp);
    k_prepack    <<<128, 256, 0, stream>>>(Wf, Uf, Wb, Ub, fragp);
    k_lstm       <<<256, 512, 0, stream>>>(xnp, fragp, mwords, bfv, bbv, hcat);
    k_head       <<<1, 1024, 0, stream>>>(hcat, g2, b2, Wd, bd, (float*)d_out);
}